// Round 1
// baseline (654.778 us; speedup 1.0000x reference)
//
#include <hip/hip_runtime.h>
#include <cstdint>
#include <cstddef>

// ---------------------------------------------------------------------------
// GCN: 3x GraphConv(norm='both') + linear head, fp32.
//   deg_out = clip(segsum(1,src),1); deg_in = clip(segsum(1,dst),1)
//   conv(x,W,b): h = (x * rsqrt(deg_out)) @ W ; agg = segsum(h[src],dst)
//                out = agg * rsqrt(deg_in) + b
//   out = elu(conv2(elu(conv1(elu(conv0(x)))))) @ Wl + bl
// Strategy: per-call CSR-by-dst build, gather-based SpMM (no float atomics),
// inv_out fused into GEMM load, inv_in+bias+ELU fused into agg epilogue.
// ---------------------------------------------------------------------------

__global__ __launch_bounds__(256) void zero_kernel(int* __restrict__ p, int n) {
  int i = blockIdx.x * 256 + threadIdx.x;
  if (i < n) p[i] = 0;
}

__global__ __launch_bounds__(256) void deg_kernel(const int* __restrict__ src,
                                                  const int* __restrict__ dst,
                                                  int* __restrict__ dego,
                                                  int* __restrict__ degi, int E) {
  int i = blockIdx.x * 256 + threadIdx.x;
  if (i < E) {
    atomicAdd(&dego[src[i]], 1);
    atomicAdd(&degi[dst[i]], 1);
  }
}

__global__ __launch_bounds__(256) void inv_kernel(const int* __restrict__ dego,
                                                  const int* __restrict__ degi,
                                                  float* __restrict__ invo,
                                                  float* __restrict__ invi, int N) {
  int i = blockIdx.x * 256 + threadIdx.x;
  if (i < N) {
    int doo = dego[i]; if (doo < 1) doo = 1;
    int dii = degi[i]; if (dii < 1) dii = 1;
    invo[i] = rsqrtf((float)doo);
    invi[i] = rsqrtf((float)dii);
  }
}

// --- 3-kernel exclusive scan over deg_in (1024 elems per block) -------------
__global__ __launch_bounds__(256) void scan1_kernel(const int* __restrict__ degi,
                                                    int* __restrict__ texcl,
                                                    int* __restrict__ bsum, int N) {
  __shared__ int sdata[256];
  const int tid = threadIdx.x;
  const int base = blockIdx.x * 1024;
  int v[4];
  int s = 0;
#pragma unroll
  for (int j = 0; j < 4; ++j) {
    int idx = base + tid * 4 + j;
    v[j] = (idx < N) ? degi[idx] : 0;
    s += v[j];
  }
  sdata[tid] = s;
  __syncthreads();
  for (int off = 1; off < 256; off <<= 1) {
    int t = (tid >= off) ? sdata[tid - off] : 0;
    __syncthreads();
    sdata[tid] += t;
    __syncthreads();
  }
  int excl = sdata[tid] - s;  // exclusive prefix of this thread within block
  if (tid == 255) bsum[blockIdx.x] = sdata[255];
  int run = excl;
#pragma unroll
  for (int j = 0; j < 4; ++j) {
    int idx = base + tid * 4 + j;
    if (idx < N) texcl[idx] = run;
    run += v[j];
  }
}

__global__ __launch_bounds__(128) void scan2_kernel(int* __restrict__ bsum, int nb) {
  __shared__ int sd[128];
  const int tid = threadIdx.x;
  int v = (tid < nb) ? bsum[tid] : 0;
  sd[tid] = v;
  __syncthreads();
  for (int off = 1; off < 128; off <<= 1) {
    int t = (tid >= off) ? sd[tid - off] : 0;
    __syncthreads();
    sd[tid] += t;
    __syncthreads();
  }
  if (tid < nb) bsum[tid] = sd[tid] - v;  // exclusive block offsets
}

__global__ __launch_bounds__(256) void scan3_kernel(const int* __restrict__ texcl,
                                                    const int* __restrict__ bsum,
                                                    int* __restrict__ rptr,
                                                    int* __restrict__ cursor,
                                                    int N, int E) {
  int i = blockIdx.x * 256 + threadIdx.x;
  if (i < N) {
    int v = texcl[i] + bsum[i >> 10];
    rptr[i] = v;
    cursor[i] = v;
  }
  if (i == 0) rptr[N] = E;
}

__global__ __launch_bounds__(256) void scatter_kernel(const int* __restrict__ src,
                                                      const int* __restrict__ dst,
                                                      int* __restrict__ cursor,
                                                      int* __restrict__ esrc, int E) {
  int i = blockIdx.x * 256 + threadIdx.x;
  if (i < E) {
    int p = atomicAdd(&cursor[dst[i]], 1);
    esrc[p] = src[i];
  }
}

// --- dense GEMM: out[N x 64] = (rowscale ? diag(rowscale)*in : in) @ W (+bias)
// 256 threads; 64 cols x (TM rows); thread = (col = tid&63, rowgroup = tid>>6)
template <int K, int TM>
__global__ __launch_bounds__(256) void gemm_kernel(const float* __restrict__ in,
                                                   const float* __restrict__ W,
                                                   const float* __restrict__ rowscale,
                                                   const float* __restrict__ bias,
                                                   float* __restrict__ out, int N) {
  constexpr int RPT = TM / 4;  // rows per thread (4 row-groups of 64 lanes)
  __shared__ float xs[TM * K];
  __shared__ float wsm[K * 64];
  const int tid = threadIdx.x;
  const int row0 = blockIdx.x * TM;

  // stage W (K x 64, contiguous) via float4
  for (int i = tid; i < K * 16; i += 256)
    ((float4*)wsm)[i] = ((const float4*)W)[i];

  // stage x tile with optional row scaling
  for (int i = tid; i < TM * K / 4; i += 256) {
    const int fl = i * 4;
    const int r = fl / K;
    const int grow = row0 + r;
    float4 v = make_float4(0.f, 0.f, 0.f, 0.f);
    if (grow < N) {
      v = *(const float4*)(in + (size_t)grow * K + (fl & (K - 1)));
      if (rowscale) {
        const float s = rowscale[grow];
        v.x *= s; v.y *= s; v.z *= s; v.w *= s;
      }
    }
    *(float4*)(xs + fl) = v;
  }
  __syncthreads();

  const int c = tid & 63;
  const int rbase = (tid >> 6) * RPT;
  float acc[RPT];
#pragma unroll
  for (int r = 0; r < RPT; ++r) acc[r] = 0.f;

  for (int k = 0; k < K; k += 4) {
    const float w0 = wsm[(k + 0) * 64 + c];
    const float w1 = wsm[(k + 1) * 64 + c];
    const float w2 = wsm[(k + 2) * 64 + c];
    const float w3 = wsm[(k + 3) * 64 + c];
#pragma unroll
    for (int r = 0; r < RPT; ++r) {
      const float4 xv = *(const float4*)(xs + (rbase + r) * K + k);
      acc[r] += xv.x * w0 + xv.y * w1 + xv.z * w2 + xv.w * w3;
    }
  }

  const float bv = bias ? bias[c] : 0.f;
#pragma unroll
  for (int r = 0; r < RPT; ++r) {
    const int grow = row0 + rbase + r;
    if (grow < N) out[(size_t)grow * 64 + c] = acc[r] + bv;
  }
}

// --- CSR gather aggregation: out[n][c] = act(sum_{e in(n)} hp[esrc[e]][c] * invi[n] + b[c])
__global__ __launch_bounds__(256) void agg_kernel(const float* __restrict__ hp,
                                                  const int* __restrict__ rptr,
                                                  const int* __restrict__ esrc,
                                                  const float* __restrict__ invin,
                                                  const float* __restrict__ bias,
                                                  float* __restrict__ out, int N,
                                                  int apply_elu) {
  const int w = (blockIdx.x * 256 + threadIdx.x) >> 6;  // one wave per dst node
  const int lane = threadIdx.x & 63;
  if (w >= N) return;
  const int e0 = rptr[w];
  const int e1 = rptr[w + 1];
  float acc = 0.f;
  int e = e0;
  for (; e + 4 <= e1; e += 4) {
    const int s0 = esrc[e + 0];
    const int s1 = esrc[e + 1];
    const int s2 = esrc[e + 2];
    const int s3 = esrc[e + 3];
    const float a0 = hp[(size_t)s0 * 64 + lane];
    const float a1 = hp[(size_t)s1 * 64 + lane];
    const float a2 = hp[(size_t)s2 * 64 + lane];
    const float a3 = hp[(size_t)s3 * 64 + lane];
    acc += (a0 + a1) + (a2 + a3);
  }
  for (; e < e1; ++e) acc += hp[(size_t)esrc[e] * 64 + lane];
  float v = acc * invin[w] + bias[lane];
  if (apply_elu) v = (v > 0.f) ? v : expm1f(v);
  out[(size_t)w * 64 + lane] = v;
}

extern "C" void kernel_launch(void* const* d_in, const int* in_sizes, int n_in,
                              void* d_out, int out_size, void* d_ws, size_t ws_size,
                              hipStream_t stream) {
  const float* x  = (const float*)d_in[0];
  const int*   src = (const int*)d_in[1];
  const int*   dst = (const int*)d_in[2];
  const float* W0 = (const float*)d_in[3];
  const float* b0 = (const float*)d_in[4];
  const float* W1 = (const float*)d_in[5];
  const float* b1 = (const float*)d_in[6];
  const float* W2 = (const float*)d_in[7];
  const float* b2 = (const float*)d_in[8];
  const float* Wl = (const float*)d_in[9];
  const float* bl = (const float*)d_in[10];

  const int N = in_sizes[0] / 128;
  const int E = in_sizes[1];

  // workspace carve-up (4-byte units, 16B-aligned regions)
  int* wsp = (int*)d_ws;
  size_t off = 0;
  auto alloc = [&](size_t n) -> int* {
    int* p = wsp + off;
    off += (n + 3) & ~(size_t)3;
    return p;
  };
  int*   dego   = alloc(N);
  int*   degi   = alloc(N);
  float* invo   = (float*)alloc(N);
  float* invi   = (float*)alloc(N);
  int*   rptr   = alloc((size_t)N + 1);
  int*   cursor = alloc(N);
  int*   texcl  = alloc(N);
  int*   bsum   = alloc(128);
  int*   esrc   = alloc(E);
  float* hP     = (float*)alloc((size_t)N * 64);
  float* hA     = (float*)alloc((size_t)N * 64);
  float* hB     = (float*)alloc((size_t)N * 64);
  (void)ws_size; (void)n_in; (void)out_size;

  const int gE = (E + 255) / 256;
  const int gN = (N + 255) / 256;
  const int nb = (N + 1023) / 1024;

  // degrees + CSR build (per call; nothing persists across calls)
  zero_kernel<<<(2 * N + 255) / 256, 256, 0, stream>>>(dego, 2 * N);
  deg_kernel<<<gE, 256, 0, stream>>>(src, dst, dego, degi, E);
  inv_kernel<<<gN, 256, 0, stream>>>(dego, degi, invo, invi, N);
  scan1_kernel<<<nb, 256, 0, stream>>>(degi, texcl, bsum, N);
  scan2_kernel<<<1, 128, 0, stream>>>(bsum, nb);
  scan3_kernel<<<gN, 256, 0, stream>>>(texcl, bsum, rptr, cursor, N, E);
  scatter_kernel<<<gE, 256, 0, stream>>>(src, dst, cursor, esrc, E);

  // layer 0: (x*invo)@W0 -> agg -> *invi+b0 -> elu
  gemm_kernel<128, 32><<<(N + 31) / 32, 256, 0, stream>>>(x, W0, invo, nullptr, hP, N);
  agg_kernel<<<(N + 3) / 4, 256, 0, stream>>>(hP, rptr, esrc, invi, b0, hA, N, 1);
  // layer 1
  gemm_kernel<64, 64><<<(N + 63) / 64, 256, 0, stream>>>(hA, W1, invo, nullptr, hP, N);
  agg_kernel<<<(N + 3) / 4, 256, 0, stream>>>(hP, rptr, esrc, invi, b1, hB, N, 1);
  // layer 2 (+ fused elu ahead of the linear head)
  gemm_kernel<64, 64><<<(N + 63) / 64, 256, 0, stream>>>(hB, W2, invo, nullptr, hP, N);
  agg_kernel<<<(N + 3) / 4, 256, 0, stream>>>(hP, rptr, esrc, invi, b2, hA, N, 1);
  // head: elu(h2) @ Wl + bl
  gemm_kernel<64, 64><<<(N + 63) / 64, 256, 0, stream>>>(hA, Wl, nullptr, bl, (float*)d_out, N);
}

// Round 2
// 521.581 us; speedup vs baseline: 1.2554x; 1.2554x over previous
//
#include <hip/hip_runtime.h>
#include <cstdint>
#include <cstddef>

// ---------------------------------------------------------------------------
// GCN: 3x GraphConv(norm='both') + linear head, fp32.
// Round 2: replace global-atomic CSR build (deg 124us + scatter 126us) with a
// two-level LDS counting sort: coarse chunk histograms -> scans -> bucket
// scatter with LDS cursors -> per-range CSR finalize. dego via privatized LDS
// histogram slabs. Only trivial-contention global traffic remains.
// ---------------------------------------------------------------------------

#define WG 256
static constexpr int NCHUNK = 512;   // edge chunks for dst bucketing
static constexpr int RW_SH  = 8;     // range width = 256 nodes (dst>>8)
static constexpr int BPRO   = 12500; // bins per range for dego histogram
static constexpr int NCO    = 32;    // edge chunks for dego histogram

// inclusive->exclusive Hillis-Steele over 256 values in sd; returns exclusive
// prefix of v at tid, sets total. Leaves sd reusable (final barrier inside).
__device__ __forceinline__ int block_scan_excl(int v, int tid, int* sd, int& total) {
  sd[tid] = v;
  __syncthreads();
  for (int off = 1; off < 256; off <<= 1) {
    int t = (tid >= off) ? sd[tid - off] : 0;
    __syncthreads();
    sd[tid] += t;
    __syncthreads();
  }
  int incl = sd[tid];
  total = sd[255];
  __syncthreads();
  return incl - v;
}

// --- Pass A: per-chunk coarse histogram over dst ranges ---------------------
__global__ __launch_bounds__(WG) void coarse_hist_kernel(const int* __restrict__ dst,
                                                         int* __restrict__ cntA,
                                                         int NR, int E, int EPC) {
  __shared__ int cnt[512];
  const int c = blockIdx.x, tid = threadIdx.x;
  for (int i = tid; i < NR; i += WG) cnt[i] = 0;
  __syncthreads();
  const int base = c * EPC;
  for (int i = tid; i < EPC; i += WG) {
    const int e = base + i;
    if (e < E) atomicAdd(&cnt[dst[e] >> RW_SH], 1);
  }
  __syncthreads();
  for (int i = tid; i < NR; i += WG) cntA[i * NCHUNK + c] = cnt[i];
}

// --- Pass B1: per-range exclusive scan over the 512 chunks ------------------
__global__ __launch_bounds__(WG) void chunkscan_kernel(const int* __restrict__ cntA,
                                                       int* __restrict__ base_rel,
                                                       int* __restrict__ cntR) {
  __shared__ int sd[256];
  const int r = blockIdx.x, tid = threadIdx.x;
  const int row = r * NCHUNK;
  int t0, t1;
  const int v0 = cntA[row + tid];
  const int e0 = block_scan_excl(v0, tid, sd, t0);
  base_rel[row + tid] = e0;
  const int v1 = cntA[row + 256 + tid];
  const int e1 = block_scan_excl(v1, tid, sd, t1);
  base_rel[row + 256 + tid] = t0 + e1;
  if (tid == 0) cntR[r] = t0 + t1;
}

// --- Pass B2: exclusive scan over ranges -> rangeStart ----------------------
__global__ __launch_bounds__(WG) void rangescan_kernel(const int* __restrict__ cntR,
                                                       int* __restrict__ rangeStart,
                                                       int* __restrict__ rptr,
                                                       int NR, int N, int E) {
  __shared__ int sd[256];
  const int tid = threadIdx.x;
  int t0, t1;
  const int v0 = (tid < NR) ? cntR[tid] : 0;
  const int e0 = block_scan_excl(v0, tid, sd, t0);
  if (tid < NR) rangeStart[tid] = e0;
  const int i1 = 256 + tid;
  const int v1 = (i1 < NR) ? cntR[i1] : 0;
  const int e1 = block_scan_excl(v1, tid, sd, t1);
  if (i1 < NR) rangeStart[i1] = t0 + e1;
  if (tid == 0) { rangeStart[NR] = E; rptr[N] = E; }
}

// --- Pass C: bucket scatter with LDS cursors --------------------------------
__global__ __launch_bounds__(WG) void bucket_kernel(const int* __restrict__ src,
                                                    const int* __restrict__ dst,
                                                    const int* __restrict__ base_rel,
                                                    const int* __restrict__ rangeStart,
                                                    int2* __restrict__ bucket,
                                                    int NR, int E, int EPC) {
  __shared__ int cur[512];
  const int c = blockIdx.x, tid = threadIdx.x;
  for (int i = tid; i < NR; i += WG) cur[i] = rangeStart[i] + base_rel[i * NCHUNK + c];
  __syncthreads();
  const int base = c * EPC;
  for (int i = tid; i < EPC; i += WG) {
    const int e = base + i;
    if (e < E) {
      const int s = src[e], d = dst[e];
      const int p = atomicAdd(&cur[d >> RW_SH], 1);
      bucket[p] = make_int2(s, d);
    }
  }
}

// --- Pass D: per-range CSR finalize (rptr, degi, esrc) ----------------------
__global__ __launch_bounds__(WG) void csr_kernel(const int2* __restrict__ bucket,
                                                 const int* __restrict__ rangeStart,
                                                 int* __restrict__ rptr,
                                                 int* __restrict__ degi,
                                                 int* __restrict__ esrc, int N) {
  __shared__ int hist[256], sd[256];
  const int r = blockIdx.x, tid = threadIdx.x;
  const int s0 = rangeStart[r], s1 = rangeStart[r + 1];
  hist[tid] = 0;
  __syncthreads();
  for (int e = s0 + tid; e < s1; e += WG) atomicAdd(&hist[bucket[e].y & 255], 1);
  __syncthreads();
  const int v = hist[tid];
  int tot;
  const int excl = block_scan_excl(v, tid, sd, tot);
  const int node = (r << RW_SH) + tid;
  if (node < N) { degi[node] = v; rptr[node] = s0 + excl; }
  hist[tid] = s0 + excl;  // reuse as absolute cursor
  __syncthreads();
  for (int e = s0 + tid; e < s1; e += WG) {
    const int2 sdv = bucket[e];
    const int p = atomicAdd(&hist[sdv.y & 255], 1);
    esrc[p] = sdv.x;
  }
}

// --- dego: privatized LDS histogram over src, slab + reduce -----------------
__global__ __launch_bounds__(WG) void dego_hist_kernel(const int* __restrict__ src,
                                                       int* __restrict__ slab,
                                                       int N, int E, int EPCO) {
  __shared__ int h[BPRO];  // 50 KB
  const int rr = blockIdx.x / NCO, cc = blockIdx.x % NCO;
  const int tid = threadIdx.x;
  for (int i = tid; i < BPRO; i += WG) h[i] = 0;
  __syncthreads();
  const int lo = rr * BPRO;
  const int base = cc * EPCO;
  for (int i = tid; i < EPCO; i += WG) {
    const int e = base + i;
    if (e < E) {
      const unsigned b = (unsigned)(src[e] - lo);
      if (b < (unsigned)BPRO) atomicAdd(&h[b], 1);
    }
  }
  __syncthreads();
  for (int i = tid; i < BPRO; i += WG) {
    const int g = lo + i;
    if (g < N) slab[(size_t)cc * N + g] = h[i];
  }
}

__global__ __launch_bounds__(WG) void dego_reduce_kernel(const int* __restrict__ slab,
                                                         int* __restrict__ dego, int N) {
  const int i = blockIdx.x * WG + threadIdx.x;
  if (i >= N) return;
  int s = 0;
#pragma unroll
  for (int c = 0; c < NCO; ++c) s += slab[(size_t)c * N + i];
  dego[i] = s;
}

__global__ __launch_bounds__(WG) void inv_kernel(const int* __restrict__ dego,
                                                 const int* __restrict__ degi,
                                                 float* __restrict__ invo,
                                                 float* __restrict__ invi, int N) {
  const int i = blockIdx.x * WG + threadIdx.x;
  if (i < N) {
    int doo = dego[i]; if (doo < 1) doo = 1;
    int dii = degi[i]; if (dii < 1) dii = 1;
    invo[i] = rsqrtf((float)doo);
    invi[i] = rsqrtf((float)dii);
  }
}

// --- dense GEMM: out[N x 64] = (rowscale ? diag(rowscale)*in : in) @ W (+bias)
template <int K, int TM>
__global__ __launch_bounds__(256) void gemm_kernel(const float* __restrict__ in,
                                                   const float* __restrict__ W,
                                                   const float* __restrict__ rowscale,
                                                   const float* __restrict__ bias,
                                                   float* __restrict__ out, int N) {
  constexpr int RPT = TM / 4;
  __shared__ float xs[TM * K];
  __shared__ float wsm[K * 64];
  const int tid = threadIdx.x;
  const int row0 = blockIdx.x * TM;

  for (int i = tid; i < K * 16; i += 256)
    ((float4*)wsm)[i] = ((const float4*)W)[i];

  for (int i = tid; i < TM * K / 4; i += 256) {
    const int fl = i * 4;
    const int r = fl / K;
    const int grow = row0 + r;
    float4 v = make_float4(0.f, 0.f, 0.f, 0.f);
    if (grow < N) {
      v = *(const float4*)(in + (size_t)grow * K + (fl & (K - 1)));
      if (rowscale) {
        const float s = rowscale[grow];
        v.x *= s; v.y *= s; v.z *= s; v.w *= s;
      }
    }
    *(float4*)(xs + fl) = v;
  }
  __syncthreads();

  const int c = tid & 63;
  const int rbase = (tid >> 6) * RPT;
  float acc[RPT];
#pragma unroll
  for (int r = 0; r < RPT; ++r) acc[r] = 0.f;

  for (int k = 0; k < K; k += 4) {
    const float w0 = wsm[(k + 0) * 64 + c];
    const float w1 = wsm[(k + 1) * 64 + c];
    const float w2 = wsm[(k + 2) * 64 + c];
    const float w3 = wsm[(k + 3) * 64 + c];
#pragma unroll
    for (int r = 0; r < RPT; ++r) {
      const float4 xv = *(const float4*)(xs + (rbase + r) * K + k);
      acc[r] += xv.x * w0 + xv.y * w1 + xv.z * w2 + xv.w * w3;
    }
  }

  const float bv = bias ? bias[c] : 0.f;
#pragma unroll
  for (int r = 0; r < RPT; ++r) {
    const int grow = row0 + rbase + r;
    if (grow < N) out[(size_t)grow * 64 + c] = acc[r] + bv;
  }
}

// --- CSR gather aggregation: out[n][c] = act(sum hp[esrc[e]][c] * invi[n] + b[c])
__global__ __launch_bounds__(256) void agg_kernel(const float* __restrict__ hp,
                                                  const int* __restrict__ rptr,
                                                  const int* __restrict__ esrc,
                                                  const float* __restrict__ invin,
                                                  const float* __restrict__ bias,
                                                  float* __restrict__ out, int N,
                                                  int apply_elu) {
  const int w = (blockIdx.x * 256 + threadIdx.x) >> 6;  // one wave per dst node
  const int lane = threadIdx.x & 63;
  if (w >= N) return;
  const int e0 = rptr[w];
  const int e1 = rptr[w + 1];
  float acc = 0.f;
  int e = e0;
  for (; e + 8 <= e1; e += 8) {
    int s[8];
#pragma unroll
    for (int j = 0; j < 8; ++j) s[j] = esrc[e + j];
    float a[8];
#pragma unroll
    for (int j = 0; j < 8; ++j) a[j] = hp[(size_t)s[j] * 64 + lane];
    acc += ((a[0] + a[1]) + (a[2] + a[3])) + ((a[4] + a[5]) + (a[6] + a[7]));
  }
  for (; e < e1; ++e) acc += hp[(size_t)esrc[e] * 64 + lane];
  float v = acc * invin[w] + bias[lane];
  if (apply_elu) v = (v > 0.f) ? v : expm1f(v);
  out[(size_t)w * 64 + lane] = v;
}

extern "C" void kernel_launch(void* const* d_in, const int* in_sizes, int n_in,
                              void* d_out, int out_size, void* d_ws, size_t ws_size,
                              hipStream_t stream) {
  const float* x  = (const float*)d_in[0];
  const int*   src = (const int*)d_in[1];
  const int*   dst = (const int*)d_in[2];
  const float* W0 = (const float*)d_in[3];
  const float* b0 = (const float*)d_in[4];
  const float* W1 = (const float*)d_in[5];
  const float* b1 = (const float*)d_in[6];
  const float* W2 = (const float*)d_in[7];
  const float* b2 = (const float*)d_in[8];
  const float* Wl = (const float*)d_in[9];
  const float* bl = (const float*)d_in[10];

  const int N = in_sizes[0] / 128;
  const int E = in_sizes[1];
  const int NR = (N + 255) >> RW_SH;            // dst ranges of 256 nodes
  const int EPC = (E + NCHUNK - 1) / NCHUNK;    // edges per chunk
  const int NRO = (N + BPRO - 1) / BPRO;        // dego ranges
  const int EPCO = (E + NCO - 1) / NCO;         // dego edges per chunk

  int* wsp = (int*)d_ws;
  size_t off = 0;
  auto alloc = [&](size_t n) -> int* {
    int* p = wsp + off;
    off += (n + 3) & ~(size_t)3;
    return p;
  };
  int*   dego       = alloc(N);
  int*   degi       = alloc(N);
  float* invo       = (float*)alloc(N);
  float* invi       = (float*)alloc(N);
  int*   rptr       = alloc((size_t)N + 1);
  int*   esrc       = alloc(E);
  int*   cntA       = alloc((size_t)NR * NCHUNK);
  int*   base_rel   = alloc((size_t)NR * NCHUNK);
  int*   cntR       = alloc(NR);
  int*   rangeStart = alloc((size_t)NR + 1);
  int2*  bucket     = (int2*)alloc((size_t)E * 2);
  int*   slab       = alloc((size_t)NCO * N);
  float* hP         = (float*)alloc((size_t)N * 64);
  float* hA         = (float*)alloc((size_t)N * 64);
  (void)ws_size; (void)n_in; (void)out_size;

  const int gN = (N + WG - 1) / WG;

  // CSR-by-dst build (atomic-free at global scope)
  coarse_hist_kernel<<<NCHUNK, WG, 0, stream>>>(dst, cntA, NR, E, EPC);
  chunkscan_kernel<<<NR, WG, 0, stream>>>(cntA, base_rel, cntR);
  rangescan_kernel<<<1, WG, 0, stream>>>(cntR, rangeStart, rptr, NR, N, E);
  bucket_kernel<<<NCHUNK, WG, 0, stream>>>(src, dst, base_rel, rangeStart, bucket, NR, E, EPC);
  csr_kernel<<<NR, WG, 0, stream>>>(bucket, rangeStart, rptr, degi, esrc, N);

  // out-degree via privatized LDS histograms
  dego_hist_kernel<<<NRO * NCO, WG, 0, stream>>>(src, slab, N, E, EPCO);
  dego_reduce_kernel<<<gN, WG, 0, stream>>>(slab, dego, N);
  inv_kernel<<<gN, WG, 0, stream>>>(dego, degi, invo, invi, N);

  // layer 0: (x*invo)@W0 -> agg -> *invi+b0 -> elu
  gemm_kernel<128, 32><<<(N + 31) / 32, 256, 0, stream>>>(x, W0, invo, nullptr, hP, N);
  agg_kernel<<<(N + 3) / 4, 256, 0, stream>>>(hP, rptr, esrc, invi, b0, hA, N, 1);
  // layer 1
  gemm_kernel<64, 64><<<(N + 63) / 64, 256, 0, stream>>>(hA, W1, invo, nullptr, hP, N);
  agg_kernel<<<(N + 3) / 4, 256, 0, stream>>>(hP, rptr, esrc, invi, b1, hA, N, 1);
  // layer 2 (+ fused elu ahead of the linear head)
  gemm_kernel<64, 64><<<(N + 63) / 64, 256, 0, stream>>>(hA, W2, invo, nullptr, hP, N);
  agg_kernel<<<(N + 3) / 4, 256, 0, stream>>>(hP, rptr, esrc, invi, b2, hA, N, 1);
  // head: elu(h2) @ Wl + bl
  gemm_kernel<64, 64><<<(N + 63) / 64, 256, 0, stream>>>(hA, Wl, nullptr, bl, (float*)d_out, N);
}

// Round 3
// 431.936 us; speedup vs baseline: 1.5159x; 1.2075x over previous
//
#include <hip/hip_runtime.h>
#include <hip/hip_fp16.h>
#include <cstdint>
#include <cstddef>

// ---------------------------------------------------------------------------
// GCN: 3x GraphConv(norm='both') + linear head, fp32 in/out.
// Round 3: fp16 gather operand (hP) halves the agg random-fetch bytes
// (260MB -> ~110MB per layer); 16-deep gather unroll for MLP; inv fused into
// dego_reduce. CSR build unchanged (atomic-free two-level counting sort).
// ---------------------------------------------------------------------------

#define WG 256
static constexpr int NCHUNK = 512;   // edge chunks for dst bucketing
static constexpr int RW_SH  = 8;     // range width = 256 nodes (dst>>8)
static constexpr int BPRO   = 12500; // bins per range for dego histogram
static constexpr int NCO    = 32;    // edge chunks for dego histogram

__device__ __forceinline__ int block_scan_excl(int v, int tid, int* sd, int& total) {
  sd[tid] = v;
  __syncthreads();
  for (int off = 1; off < 256; off <<= 1) {
    int t = (tid >= off) ? sd[tid - off] : 0;
    __syncthreads();
    sd[tid] += t;
    __syncthreads();
  }
  int incl = sd[tid];
  total = sd[255];
  __syncthreads();
  return incl - v;
}

// --- Pass A: per-chunk coarse histogram over dst ranges ---------------------
__global__ __launch_bounds__(WG) void coarse_hist_kernel(const int* __restrict__ dst,
                                                         int* __restrict__ cntA,
                                                         int NR, int E, int EPC) {
  __shared__ int cnt[512];
  const int c = blockIdx.x, tid = threadIdx.x;
  for (int i = tid; i < NR; i += WG) cnt[i] = 0;
  __syncthreads();
  const int base = c * EPC;
  for (int i = tid; i < EPC; i += WG) {
    const int e = base + i;
    if (e < E) atomicAdd(&cnt[dst[e] >> RW_SH], 1);
  }
  __syncthreads();
  for (int i = tid; i < NR; i += WG) cntA[i * NCHUNK + c] = cnt[i];
}

// --- Pass B1: per-range exclusive scan over the 512 chunks ------------------
__global__ __launch_bounds__(WG) void chunkscan_kernel(const int* __restrict__ cntA,
                                                       int* __restrict__ base_rel,
                                                       int* __restrict__ cntR) {
  __shared__ int sd[256];
  const int r = blockIdx.x, tid = threadIdx.x;
  const int row = r * NCHUNK;
  int t0, t1;
  const int v0 = cntA[row + tid];
  const int e0 = block_scan_excl(v0, tid, sd, t0);
  base_rel[row + tid] = e0;
  const int v1 = cntA[row + 256 + tid];
  const int e1 = block_scan_excl(v1, tid, sd, t1);
  base_rel[row + 256 + tid] = t0 + e1;
  if (tid == 0) cntR[r] = t0 + t1;
}

// --- Pass B2: exclusive scan over ranges -> rangeStart ----------------------
__global__ __launch_bounds__(WG) void rangescan_kernel(const int* __restrict__ cntR,
                                                       int* __restrict__ rangeStart,
                                                       int* __restrict__ rptr,
                                                       int NR, int N, int E) {
  __shared__ int sd[256];
  const int tid = threadIdx.x;
  int t0, t1;
  const int v0 = (tid < NR) ? cntR[tid] : 0;
  const int e0 = block_scan_excl(v0, tid, sd, t0);
  if (tid < NR) rangeStart[tid] = e0;
  const int i1 = 256 + tid;
  const int v1 = (i1 < NR) ? cntR[i1] : 0;
  const int e1 = block_scan_excl(v1, tid, sd, t1);
  if (i1 < NR) rangeStart[i1] = t0 + e1;
  if (tid == 0) { rangeStart[NR] = E; rptr[N] = E; }
}

// --- Pass C: bucket scatter with LDS cursors --------------------------------
__global__ __launch_bounds__(WG) void bucket_kernel(const int* __restrict__ src,
                                                    const int* __restrict__ dst,
                                                    const int* __restrict__ base_rel,
                                                    const int* __restrict__ rangeStart,
                                                    int2* __restrict__ bucket,
                                                    int NR, int E, int EPC) {
  __shared__ int cur[512];
  const int c = blockIdx.x, tid = threadIdx.x;
  for (int i = tid; i < NR; i += WG) cur[i] = rangeStart[i] + base_rel[i * NCHUNK + c];
  __syncthreads();
  const int base = c * EPC;
  for (int i = tid; i < EPC; i += WG) {
    const int e = base + i;
    if (e < E) {
      const int s = src[e], d = dst[e];
      const int p = atomicAdd(&cur[d >> RW_SH], 1);
      bucket[p] = make_int2(s, d);
    }
  }
}

// --- Pass D: per-range CSR finalize (rptr, degi, esrc) ----------------------
__global__ __launch_bounds__(WG) void csr_kernel(const int2* __restrict__ bucket,
                                                 const int* __restrict__ rangeStart,
                                                 int* __restrict__ rptr,
                                                 int* __restrict__ degi,
                                                 int* __restrict__ esrc, int N) {
  __shared__ int hist[256], sd[256];
  const int r = blockIdx.x, tid = threadIdx.x;
  const int s0 = rangeStart[r], s1 = rangeStart[r + 1];
  hist[tid] = 0;
  __syncthreads();
  for (int e = s0 + tid; e < s1; e += WG) atomicAdd(&hist[bucket[e].y & 255], 1);
  __syncthreads();
  const int v = hist[tid];
  int tot;
  const int excl = block_scan_excl(v, tid, sd, tot);
  const int node = (r << RW_SH) + tid;
  if (node < N) { degi[node] = v; rptr[node] = s0 + excl; }
  hist[tid] = s0 + excl;  // reuse as absolute cursor
  __syncthreads();
  for (int e = s0 + tid; e < s1; e += WG) {
    const int2 sdv = bucket[e];
    const int p = atomicAdd(&hist[sdv.y & 255], 1);
    esrc[p] = sdv.x;
  }
}

// --- dego: privatized LDS histogram over src, slab + reduce + inv -----------
__global__ __launch_bounds__(WG) void dego_hist_kernel(const int* __restrict__ src,
                                                       int* __restrict__ slab,
                                                       int N, int E, int EPCO) {
  __shared__ int h[BPRO];  // 50 KB
  const int rr = blockIdx.x / NCO, cc = blockIdx.x % NCO;
  const int tid = threadIdx.x;
  for (int i = tid; i < BPRO; i += WG) h[i] = 0;
  __syncthreads();
  const int lo = rr * BPRO;
  const int base = cc * EPCO;
  for (int i = tid; i < EPCO; i += WG) {
    const int e = base + i;
    if (e < E) {
      const unsigned b = (unsigned)(src[e] - lo);
      if (b < (unsigned)BPRO) atomicAdd(&h[b], 1);
    }
  }
  __syncthreads();
  for (int i = tid; i < BPRO; i += WG) {
    const int g = lo + i;
    if (g < N) slab[(size_t)cc * N + g] = h[i];
  }
}

__global__ __launch_bounds__(WG) void dego_reduce_inv_kernel(const int* __restrict__ slab,
                                                             const int* __restrict__ degi,
                                                             float* __restrict__ invo,
                                                             float* __restrict__ invi, int N) {
  const int i = blockIdx.x * WG + threadIdx.x;
  if (i >= N) return;
  int s = 0;
#pragma unroll
  for (int c = 0; c < NCO; ++c) s += slab[(size_t)c * N + i];
  if (s < 1) s = 1;
  int dii = degi[i]; if (dii < 1) dii = 1;
  invo[i] = rsqrtf((float)s);
  invi[i] = rsqrtf((float)dii);
}

// --- dense GEMM: out[N x 64] = (rowscale ? diag(rowscale)*in : in) @ W (+bias)
template <int K, int TM, typename OutT>
__global__ __launch_bounds__(256) void gemm_kernel(const float* __restrict__ in,
                                                   const float* __restrict__ W,
                                                   const float* __restrict__ rowscale,
                                                   const float* __restrict__ bias,
                                                   OutT* __restrict__ out, int N) {
  constexpr int RPT = TM / 4;
  __shared__ float xs[TM * K];
  __shared__ float wsm[K * 64];
  const int tid = threadIdx.x;
  const int row0 = blockIdx.x * TM;

  for (int i = tid; i < K * 16; i += 256)
    ((float4*)wsm)[i] = ((const float4*)W)[i];

  for (int i = tid; i < TM * K / 4; i += 256) {
    const int fl = i * 4;
    const int r = fl / K;
    const int grow = row0 + r;
    float4 v = make_float4(0.f, 0.f, 0.f, 0.f);
    if (grow < N) {
      v = *(const float4*)(in + (size_t)grow * K + (fl & (K - 1)));
      if (rowscale) {
        const float s = rowscale[grow];
        v.x *= s; v.y *= s; v.z *= s; v.w *= s;
      }
    }
    *(float4*)(xs + fl) = v;
  }
  __syncthreads();

  const int c = tid & 63;
  const int rbase = (tid >> 6) * RPT;
  float acc[RPT];
#pragma unroll
  for (int r = 0; r < RPT; ++r) acc[r] = 0.f;

  for (int k = 0; k < K; k += 4) {
    const float w0 = wsm[(k + 0) * 64 + c];
    const float w1 = wsm[(k + 1) * 64 + c];
    const float w2 = wsm[(k + 2) * 64 + c];
    const float w3 = wsm[(k + 3) * 64 + c];
#pragma unroll
    for (int r = 0; r < RPT; ++r) {
      const float4 xv = *(const float4*)(xs + (rbase + r) * K + k);
      acc[r] += xv.x * w0 + xv.y * w1 + xv.z * w2 + xv.w * w3;
    }
  }

  const float bv = bias ? bias[c] : 0.f;
#pragma unroll
  for (int r = 0; r < RPT; ++r) {
    const int grow = row0 + rbase + r;
    if (grow < N) {
      const float o = acc[r] + bv;
      out[(size_t)grow * 64 + c] = (OutT)o;
    }
  }
}

// --- CSR gather aggregation over fp16 rows ----------------------------------
// out[n][c] = elu?(sum_{e in(n)} (float)hp[esrc[e]][c] * invi[n] + b[c])
__global__ __launch_bounds__(256) void agg_kernel(const __half* __restrict__ hp,
                                                  const int* __restrict__ rptr,
                                                  const int* __restrict__ esrc,
                                                  const float* __restrict__ invin,
                                                  const float* __restrict__ bias,
                                                  float* __restrict__ out, int N,
                                                  int apply_elu) {
  const int w = (blockIdx.x * 256 + threadIdx.x) >> 6;  // one wave per dst node
  const int lane = threadIdx.x & 63;
  if (w >= N) return;
  const int e0 = rptr[w];
  const int e1 = rptr[w + 1];
  float acc = 0.f;
  int e = e0;
  for (; e + 16 <= e1; e += 16) {
    int s[16];
#pragma unroll
    for (int j = 0; j < 16; ++j) s[j] = esrc[e + j];
    float a[16];
#pragma unroll
    for (int j = 0; j < 16; ++j) a[j] = __half2float(hp[(size_t)s[j] * 64 + lane]);
    float p0 = ((a[0] + a[1]) + (a[2] + a[3])) + ((a[4] + a[5]) + (a[6] + a[7]));
    float p1 = ((a[8] + a[9]) + (a[10] + a[11])) + ((a[12] + a[13]) + (a[14] + a[15]));
    acc += p0 + p1;
  }
  for (; e + 4 <= e1; e += 4) {
    int s[4];
#pragma unroll
    for (int j = 0; j < 4; ++j) s[j] = esrc[e + j];
    float a[4];
#pragma unroll
    for (int j = 0; j < 4; ++j) a[j] = __half2float(hp[(size_t)s[j] * 64 + lane]);
    acc += (a[0] + a[1]) + (a[2] + a[3]);
  }
  for (; e < e1; ++e) acc += __half2float(hp[(size_t)esrc[e] * 64 + lane]);
  float v = acc * invin[w] + bias[lane];
  if (apply_elu) v = (v > 0.f) ? v : expm1f(v);
  out[(size_t)w * 64 + lane] = v;
}

extern "C" void kernel_launch(void* const* d_in, const int* in_sizes, int n_in,
                              void* d_out, int out_size, void* d_ws, size_t ws_size,
                              hipStream_t stream) {
  const float* x  = (const float*)d_in[0];
  const int*   src = (const int*)d_in[1];
  const int*   dst = (const int*)d_in[2];
  const float* W0 = (const float*)d_in[3];
  const float* b0 = (const float*)d_in[4];
  const float* W1 = (const float*)d_in[5];
  const float* b1 = (const float*)d_in[6];
  const float* W2 = (const float*)d_in[7];
  const float* b2 = (const float*)d_in[8];
  const float* Wl = (const float*)d_in[9];
  const float* bl = (const float*)d_in[10];

  const int N = in_sizes[0] / 128;
  const int E = in_sizes[1];
  const int NR = (N + 255) >> RW_SH;
  const int EPC = (E + NCHUNK - 1) / NCHUNK;
  const int NRO = (N + BPRO - 1) / BPRO;
  const int EPCO = (E + NCO - 1) / NCO;

  int* wsp = (int*)d_ws;
  size_t off = 0;
  auto alloc = [&](size_t n) -> int* {   // 256B-aligned regions
    int* p = wsp + off;
    off += (n + 63) & ~(size_t)63;
    return p;
  };
  int*    dego       = alloc(N);  (void)dego;
  int*    degi       = alloc(N);
  float*  invo       = (float*)alloc(N);
  float*  invi       = (float*)alloc(N);
  int*    rptr       = alloc((size_t)N + 1);
  int*    esrc       = alloc(E);
  int*    cntA       = alloc((size_t)NR * NCHUNK);
  int*    base_rel   = alloc((size_t)NR * NCHUNK);
  int*    cntR       = alloc(NR);
  int*    rangeStart = alloc((size_t)NR + 1);
  int2*   bucket     = (int2*)alloc((size_t)E * 2);
  int*    slab       = alloc((size_t)NCO * N);
  __half* hP         = (__half*)alloc((size_t)N * 32);  // N x 64 fp16
  float*  hA         = (float*)alloc((size_t)N * 64);
  (void)ws_size; (void)n_in; (void)out_size;

  const int gN = (N + WG - 1) / WG;

  // CSR-by-dst build (atomic-free at global scope)
  coarse_hist_kernel<<<NCHUNK, WG, 0, stream>>>(dst, cntA, NR, E, EPC);
  chunkscan_kernel<<<NR, WG, 0, stream>>>(cntA, base_rel, cntR);
  rangescan_kernel<<<1, WG, 0, stream>>>(cntR, rangeStart, rptr, NR, N, E);
  bucket_kernel<<<NCHUNK, WG, 0, stream>>>(src, dst, base_rel, rangeStart, bucket, NR, E, EPC);
  csr_kernel<<<NR, WG, 0, stream>>>(bucket, rangeStart, rptr, degi, esrc, N);

  // out-degree via privatized LDS histograms + fused inv
  dego_hist_kernel<<<NRO * NCO, WG, 0, stream>>>(src, slab, N, E, EPCO);
  dego_reduce_inv_kernel<<<gN, WG, 0, stream>>>(slab, degi, invo, invi, N);

  // layer 0: (x*invo)@W0 -> agg -> *invi+b0 -> elu
  gemm_kernel<128, 32, __half><<<(N + 31) / 32, 256, 0, stream>>>(x, W0, invo, nullptr, hP, N);
  agg_kernel<<<(N + 3) / 4, 256, 0, stream>>>(hP, rptr, esrc, invi, b0, hA, N, 1);
  // layer 1
  gemm_kernel<64, 64, __half><<<(N + 63) / 64, 256, 0, stream>>>(hA, W1, invo, nullptr, hP, N);
  agg_kernel<<<(N + 3) / 4, 256, 0, stream>>>(hP, rptr, esrc, invi, b1, hA, N, 1);
  // layer 2 (+ fused elu ahead of the linear head)
  gemm_kernel<64, 64, __half><<<(N + 63) / 64, 256, 0, stream>>>(hA, W2, invo, nullptr, hP, N);
  agg_kernel<<<(N + 3) / 4, 256, 0, stream>>>(hP, rptr, esrc, invi, b2, hA, N, 1);
  // head: elu(h2) @ Wl + bl
  gemm_kernel<64, 64, float><<<(N + 63) / 64, 256, 0, stream>>>(hA, Wl, nullptr, bl, (float*)d_out, N);
}